// Round 6
// baseline (152.795 us; speedup 1.0000x reference)
//
#include <hip/hip_runtime.h>

// Problem constants: B=8, N=16384, S=1024, T=2, D=3
#define NPTS 16384
#define SPTS 1024

typedef _Float16 half8 __attribute__((ext_vector_type(8)));
typedef float float16 __attribute__((ext_vector_type(16)));

union H8 { _Float16 h[8]; half8 v; uint4 q4; };

// min across each 32-lane half (validated r6/r7, absmax 0)
__device__ inline float wave32_min(float v) {
    v = fminf(v, __int_as_float(__builtin_amdgcn_mov_dpp(__float_as_int(v), 0xB1, 0xF, 0xF, true)));
    v = fminf(v, __int_as_float(__builtin_amdgcn_mov_dpp(__float_as_int(v), 0x4E, 0xF, 0xF, true)));
    v = fminf(v, __int_as_float(__builtin_amdgcn_mov_dpp(__float_as_int(v), 0x141, 0xF, 0xF, true)));
    v = fminf(v, __int_as_float(__builtin_amdgcn_mov_dpp(__float_as_int(v), 0x140, 0xF, 0xF, true)));
    v = fminf(v, __int_as_float(__builtin_amdgcn_ds_swizzle(__float_as_int(v), 0x401F)));
    return v;
}

// 3-way min shaped for LLVM's v_min3_f32 fusion (no inline asm: r9 hazard lesson).
__device__ inline float min3f(float a, float b, float c) {
    return fminf(fminf(a, b), c);
}

// r14. r13 counters: Occ 27%, MfmaUtil 11%, VALUBusy 27%, bank-conflicts 1.29M
// (11.7x r11) -> latency-bound at ~2.2 waves/SIMD + 32x-redundant gt staging in
// the col pass (768 blocks each staging all 16384 gt in 16 LDS rounds).
// Fix: (a) col pass 768->192 blocks, 128 sp each (wave owns one 32-sp A-tile,
// sweeps all 32 B-tiles/round) -> 4x less staging redundancy. (b) grid = 1024
// blocks exactly = 4/CU at __launch_bounds__(256,4) -> one generation, 16
// waves/CU. VGPR: r13 used 84 @cap170; col loop live ~100 < cap 128. r8 spill
// cliff was 4-deep MFMA + extra frags; we stay 2-deep.
// Block map: [0,768) row pass | [768,960) col pass | [960,1024) MSE.

__global__ __launch_bounds__(256, 4) void fused_kernel(
    const float* __restrict__ gt,   // [8,16384,3]
    const float* __restrict__ sp,   // [8,1024,3]
    const float* __restrict__ tgt,  // [16,16384,3]
    const float* __restrict__ tsp,  // [16,1024,3]
    const float* __restrict__ tm,   // [2,3,3]
    unsigned int* __restrict__ counters,  // [0]=master
    float* __restrict__ partials,         // [1024]
    float* __restrict__ out)
{
    const int bid = blockIdx.x;
    const int tid = threadIdx.x;
    const int lane = tid & 63;
    const int lh = lane & 31;
    const int w = tid >> 6;  // wave 0..3

    __shared__ uint4 s_frag4[1584];  // B tiles [0,1056) + A tiles [1056,1584) = 25.3 KB
    __shared__ float redbuf[4];
    __shared__ int flag;

    float16 z16 = {0.f,0.f,0.f,0.f,0.f,0.f,0.f,0.f,0.f,0.f,0.f,0.f,0.f,0.f,0.f,0.f};

    if (bid >= 960) {
        // ---------------- consistency MSE (fp32 exact), 64 blocks ----------------
        int idx = (bid - 960) * 256 + tid;  // over (t,b,s) = 2*8*1024
        int t = idx >> 13;
        int bs = idx & 8191;
        const float* p = sp + (size_t)bs * 3;
        float x = p[0], y = p[1], z = p[2];
        const float* m = tm + t * 9;
        const float* q = tsp + (size_t)idx * 3;
        float acc = 0.f;
#pragma unroll
        for (int e = 0; e < 3; e++) {
            float v = fmaf(x, m[e], fmaf(y, m[3 + e], z * m[6 + e]));
            float d = v - q[e];
            acc = fmaf(d, d, acc);
        }
        for (int o = 32; o > 0; o >>= 1) acc += __shfl_down(acc, o, 64);
        if (lane == 0) redbuf[w] = acc;
        __syncthreads();
        if (tid == 0)
            partials[bid] = (redbuf[0] + redbuf[1] + redbuf[2] + redbuf[3])
                            * (1000.f / (2.f * 8.f * 1024.f * 3.f));
    } else if (bid < 768) {
        // ---------------- row pass: gt-side min (over sp), block-local ----------------
        int bb = bid >> 5;         // 24 batches
        int mc = bid & 31;         // 512-row gt chunk
        const float* spp = (bb < 8) ? sp + (size_t)bb * SPTS * 3
                                    : tsp + (size_t)(bb - 8) * SPTS * 3;
        const float* qp  = (bb < 8) ? gt + (size_t)bb * NPTS * 3
                                    : tgt + (size_t)(bb - 8) * NPTS * 3;

        // zero slots for all 48 tiles (32 sp B + 16 gt A)
        if (tid < 48) s_frag4[tid * 33 + 32] = make_uint4(0, 0, 0, 0);
        // stage sp B-frags (1024 points)
        for (int i = tid; i < 1024; i += 256) {
            const float* pp = spp + (size_t)i * 3;
            float sx = pp[0], sy = pp[1], sz = pp[2];
            H8 bf; bf.q4 = make_uint4(0, 0, 0, 0);
            bf.h[0] = (_Float16)(-2.f * sx); bf.h[1] = (_Float16)(-2.f * sy);
            bf.h[2] = (_Float16)(-2.f * sz); bf.h[3] = (_Float16)1.f;
            bf.h[4] = (_Float16)(sx * sx + sy * sy + sz * sz);
            s_frag4[(i >> 5) * 33 + (i & 31)] = bf.q4;
        }
        // stage gt A-frags (512 points of this chunk)
        for (int i = tid; i < 512; i += 256) {
            const float* pp = qp + (size_t)(mc * 512 + i) * 3;
            float x = pp[0], y = pp[1], z = pp[2];
            H8 af; af.q4 = make_uint4(0, 0, 0, 0);
            af.h[0] = (_Float16)x; af.h[1] = (_Float16)y; af.h[2] = (_Float16)z;
            af.h[3] = (_Float16)(x * x + y * y + z * z); af.h[4] = (_Float16)1.f;
            s_frag4[1056 + (i >> 5) * 33 + (i & 31)] = af.q4;
        }
        __syncthreads();

        const char* lds = (const char*)s_frag4;
        const int laneoff = (lane < 32) ? lh * 16 : 512;
        const char* bBase = lds + laneoff;
        const char* aBase = lds + 1056 * 16 + laneoff;

        float wsum = 0.f;
        for (int mi = 0; mi < 4; mi++) {
            int mt = w * 4 + mi;  // this wave's m-tile (0..15)
            H8 a; a.q4 = *(const uint4*)(aBase + mt * 528);
            float rm[16];
#pragma unroll
            for (int r = 0; r < 16; r++) rm[r] = 1e30f;
#pragma unroll
            for (int t = 0; t < 32; t += 2) {
                H8 b0; b0.q4 = *(const uint4*)(bBase + t * 528);
                H8 b1; b1.q4 = *(const uint4*)(bBase + (t + 1) * 528);
                float16 d0 = __builtin_amdgcn_mfma_f32_32x32x16_f16(a.v, b0.v, z16, 0, 0, 0);
                float16 d1 = __builtin_amdgcn_mfma_f32_32x32x16_f16(a.v, b1.v, z16, 0, 0, 0);
#pragma unroll
                for (int r = 0; r < 16; r++) rm[r] = min3f(rm[r], d0[r], d1[r]);
            }
            float tsum = 0.f;
#pragma unroll
            for (int r = 0; r < 16; r++) tsum += wave32_min(rm[r]);
            wsum += tsum;
        }
        wsum += __shfl_xor(wsum, 32, 64);
        if (lane == 0) redbuf[w] = wsum;
        __syncthreads();
        if (tid == 0) {
            float scale = (bb < 8) ? 1.f / (2.f * 3.f * 8.f * 16384.f)
                                   : 1.f / (2.f * 3.f * 16.f * 16384.f);
            partials[bid] = (redbuf[0] + redbuf[1] + redbuf[2] + redbuf[3]) * scale;
        }
    } else {
        // ---- col pass: sp-side min (over gt), block-local. 192 blocks x 128 sp ----
        int c = bid - 768;
        int bb = c >> 3;           // 24 batches
        int sc = c & 7;            // 128-point sp chunk
        const float* spp = (bb < 8) ? sp + (size_t)bb * SPTS * 3
                                    : tsp + (size_t)(bb - 8) * SPTS * 3;
        const float* qp  = (bb < 8) ? gt + (size_t)bb * NPTS * 3
                                    : tgt + (size_t)(bb - 8) * NPTS * 3;

        // zero slots: 32 B tiles + 4 A tiles
        if (tid < 36)
            s_frag4[(tid < 32) ? (tid * 33 + 32) : (1056 + (tid - 32) * 33 + 32)] =
                make_uint4(0, 0, 0, 0);
        // stage A-frags: this block's 128 sp points (A format: [x,y,z,|p|^2,1])
        if (tid < 128) {
            const float* pp = spp + (size_t)(sc * 128 + tid) * 3;
            float sx = pp[0], sy = pp[1], sz = pp[2];
            H8 af; af.q4 = make_uint4(0, 0, 0, 0);
            af.h[0] = (_Float16)sx; af.h[1] = (_Float16)sy; af.h[2] = (_Float16)sz;
            af.h[3] = (_Float16)(sx * sx + sy * sy + sz * sz); af.h[4] = (_Float16)1.f;
            s_frag4[1056 + (tid >> 5) * 33 + (tid & 31)] = af.q4;
        }

        const char* lds = (const char*)s_frag4;
        const int laneoff = (lane < 32) ? lh * 16 : 512;
        const char* bBase = lds + laneoff;
        const char* aBase = lds + 1056 * 16 + laneoff;

        H8 a;
        float rm[16];
#pragma unroll
        for (int r = 0; r < 16; r++) rm[r] = 1e30f;

        for (int g = 0; g < 16; g++) {
            if (g) __syncthreads();  // protect B-region overwrite
            // stage gt B-frags: points [g*1024, g*1024+1024)
            for (int i = tid; i < 1024; i += 256) {
                const float* pp = qp + (size_t)(g * 1024 + i) * 3;
                float x = pp[0], y = pp[1], z = pp[2];
                H8 bf; bf.q4 = make_uint4(0, 0, 0, 0);
                bf.h[0] = (_Float16)(-2.f * x); bf.h[1] = (_Float16)(-2.f * y);
                bf.h[2] = (_Float16)(-2.f * z); bf.h[3] = (_Float16)1.f;
                bf.h[4] = (_Float16)(x * x + y * y + z * z);
                s_frag4[(i >> 5) * 33 + (i & 31)] = bf.q4;
            }
            __syncthreads();
            if (g == 0) a.q4 = *(const uint4*)(aBase + w * 528);  // wave's sp A-tile
#pragma unroll
            for (int t = 0; t < 32; t += 2) {
                H8 b0; b0.q4 = *(const uint4*)(bBase + t * 528);
                H8 b1; b1.q4 = *(const uint4*)(bBase + (t + 1) * 528);
                float16 d0 = __builtin_amdgcn_mfma_f32_32x32x16_f16(a.v, b0.v, z16, 0, 0, 0);
                float16 d1 = __builtin_amdgcn_mfma_f32_32x32x16_f16(a.v, b1.v, z16, 0, 0, 0);
#pragma unroll
                for (int r = 0; r < 16; r++) rm[r] = min3f(rm[r], d0[r], d1[r]);
            }
        }
        // wave-local: min over lanes (gt cols) -> sum this wave's 32 sp rows
        float tsum = 0.f;
#pragma unroll
        for (int r = 0; r < 16; r++) tsum += wave32_min(rm[r]);
        tsum += __shfl_xor(tsum, 32, 64);  // add other half's 16 rows
        if (lane == 0) redbuf[w] = tsum;
        __syncthreads();
        if (tid == 0) {
            float scale = (bb < 8) ? 1.f / (2.f * 3.f * 8.f * 1024.f)
                                   : 1.f / (2.f * 3.f * 16.f * 1024.f);
            partials[bid] = (redbuf[0] + redbuf[1] + redbuf[2] + redbuf[3]) * scale;
        }
    }

    // ---------------- master counter: last block sums all partials -> out ----------------
    __syncthreads();
    if (tid == 0) {
        __threadfence();
        unsigned int old = atomicAdd(&counters[0], 1u);
        flag = (old == 1023u);
    }
    __syncthreads();
    if (flag) {
        __threadfence();
        float s2 = 0.f;
        for (int i = tid; i < 1024; i += 256) s2 += partials[i];
        for (int o = 32; o > 0; o >>= 1) s2 += __shfl_down(s2, o, 64);
        if (lane == 0) redbuf[w] = s2;
        __syncthreads();
        if (tid == 0) out[0] = redbuf[0] + redbuf[1] + redbuf[2] + redbuf[3];
    }
}

extern "C" void kernel_launch(void* const* d_in, const int* in_sizes, int n_in,
                              void* d_out, int out_size, void* d_ws, size_t ws_size,
                              hipStream_t stream) {
    const float* gt  = (const float*)d_in[0];  // gt_points [8,16384,3]
    const float* sp  = (const float*)d_in[1];  // structure_points [8,1024,3]
    const float* tgt = (const float*)d_in[2];  // transed_gt_points [2,8,16384,3]
    const float* tsp = (const float*)d_in[3];  // transed_structure_points [2,8,1024,3]
    const float* tm  = (const float*)d_in[4];  // trans_mats [2,3,3]

    unsigned int* counters = (unsigned int*)d_ws;
    float* partials = (float*)((char*)d_ws + 64);  // 1024 floats

    hipMemsetAsync(d_ws, 0, 64, stream);  // master counter

    fused_kernel<<<1024, 256, 0, stream>>>(gt, sp, tgt, tsp, tm, counters, partials,
                                           (float*)d_out);
}

// Round 7
// 130.294 us; speedup vs baseline: 1.1727x; 1.1727x over previous
//
#include <hip/hip_runtime.h>

// Problem constants: B=8, N=16384, S=1024, T=2, D=3
#define NPTS 16384
#define SPTS 1024

typedef _Float16 half8 __attribute__((ext_vector_type(8)));
typedef float float16 __attribute__((ext_vector_type(16)));

union H8 { _Float16 h[8]; half8 v; uint4 q4; };

// min across each 32-lane half (validated r6/r7, absmax 0)
__device__ inline float wave32_min(float v) {
    v = fminf(v, __int_as_float(__builtin_amdgcn_mov_dpp(__float_as_int(v), 0xB1, 0xF, 0xF, true)));
    v = fminf(v, __int_as_float(__builtin_amdgcn_mov_dpp(__float_as_int(v), 0x4E, 0xF, 0xF, true)));
    v = fminf(v, __int_as_float(__builtin_amdgcn_mov_dpp(__float_as_int(v), 0x141, 0xF, 0xF, true)));
    v = fminf(v, __int_as_float(__builtin_amdgcn_mov_dpp(__float_as_int(v), 0x140, 0xF, 0xF, true)));
    v = fminf(v, __int_as_float(__builtin_amdgcn_ds_swizzle(__float_as_int(v), 0x401F)));
    return v;
}

// 3-way min shaped for LLVM's v_min3_f32 fusion (no inline asm: r9 hazard lesson).
__device__ inline float min3f(float a, float b, float c) {
    return fminf(fminf(a, b), c);
}

// r15. r14 counters: VGPR 64 (down from 84) + FETCH 105MB + WRITE 43MB = the r8
// spill cliff again -- __launch_bounds__(256,4) caps total regs at 128, col-loop
// live state ~100 arch VGPRs + AGPR accs doesn't fit, compiler spills. REVERT to
// (256,3) (cap 170). **RULE: this kernel never uses (256,4).**
// Second fix: block-role ORDER. Col waves do 512 MFMAs vs row waves' 128; r14 put
// the 192 long col blocks last -> low-occupancy 4x-long tail. Now col blocks are
// bid [0,192) (dispatched first), row [192,960), MSE [960,1024).
// Structure unchanged otherwise: two passes, reduction axis block-local, no
// atomics (1 counter add/block), partials[1024] + master-counter final sum.

__global__ __launch_bounds__(256, 3) void fused_kernel(
    const float* __restrict__ gt,   // [8,16384,3]
    const float* __restrict__ sp,   // [8,1024,3]
    const float* __restrict__ tgt,  // [16,16384,3]
    const float* __restrict__ tsp,  // [16,1024,3]
    const float* __restrict__ tm,   // [2,3,3]
    unsigned int* __restrict__ counters,  // [0]=master
    float* __restrict__ partials,         // [1024]
    float* __restrict__ out)
{
    const int bid = blockIdx.x;
    const int tid = threadIdx.x;
    const int lane = tid & 63;
    const int lh = lane & 31;
    const int w = tid >> 6;  // wave 0..3

    __shared__ uint4 s_frag4[1584];  // B tiles [0,1056) + A tiles [1056,1584) = 25.3 KB
    __shared__ float redbuf[4];
    __shared__ int flag;

    float16 z16 = {0.f,0.f,0.f,0.f,0.f,0.f,0.f,0.f,0.f,0.f,0.f,0.f,0.f,0.f,0.f,0.f};

    if (bid >= 960) {
        // ---------------- consistency MSE (fp32 exact), 64 blocks ----------------
        int idx = (bid - 960) * 256 + tid;  // over (t,b,s) = 2*8*1024
        int t = idx >> 13;
        int bs = idx & 8191;
        const float* p = sp + (size_t)bs * 3;
        float x = p[0], y = p[1], z = p[2];
        const float* m = tm + t * 9;
        const float* q = tsp + (size_t)idx * 3;
        float acc = 0.f;
#pragma unroll
        for (int e = 0; e < 3; e++) {
            float v = fmaf(x, m[e], fmaf(y, m[3 + e], z * m[6 + e]));
            float d = v - q[e];
            acc = fmaf(d, d, acc);
        }
        for (int o = 32; o > 0; o >>= 1) acc += __shfl_down(acc, o, 64);
        if (lane == 0) redbuf[w] = acc;
        __syncthreads();
        if (tid == 0)
            partials[bid] = (redbuf[0] + redbuf[1] + redbuf[2] + redbuf[3])
                            * (1000.f / (2.f * 8.f * 1024.f * 3.f));
    } else if (bid < 192) {
        // ---- col pass FIRST (long blocks): sp-side min (over gt), 192 x 128 sp ----
        int bb = bid >> 3;         // 24 batches
        int sc = bid & 7;          // 128-point sp chunk
        const float* spp = (bb < 8) ? sp + (size_t)bb * SPTS * 3
                                    : tsp + (size_t)(bb - 8) * SPTS * 3;
        const float* qp  = (bb < 8) ? gt + (size_t)bb * NPTS * 3
                                    : tgt + (size_t)(bb - 8) * NPTS * 3;

        // zero slots: 32 B tiles + 4 A tiles
        if (tid < 36)
            s_frag4[(tid < 32) ? (tid * 33 + 32) : (1056 + (tid - 32) * 33 + 32)] =
                make_uint4(0, 0, 0, 0);
        // stage A-frags: this block's 128 sp points (A format: [x,y,z,|p|^2,1])
        if (tid < 128) {
            const float* pp = spp + (size_t)(sc * 128 + tid) * 3;
            float sx = pp[0], sy = pp[1], sz = pp[2];
            H8 af; af.q4 = make_uint4(0, 0, 0, 0);
            af.h[0] = (_Float16)sx; af.h[1] = (_Float16)sy; af.h[2] = (_Float16)sz;
            af.h[3] = (_Float16)(sx * sx + sy * sy + sz * sz); af.h[4] = (_Float16)1.f;
            s_frag4[1056 + (tid >> 5) * 33 + (tid & 31)] = af.q4;
        }

        const char* lds = (const char*)s_frag4;
        const int laneoff = (lane < 32) ? lh * 16 : 512;
        const char* bBase = lds + laneoff;
        const char* aBase = lds + 1056 * 16 + laneoff;

        H8 a;
        float rm[16];
#pragma unroll
        for (int r = 0; r < 16; r++) rm[r] = 1e30f;

        for (int g = 0; g < 16; g++) {
            if (g) __syncthreads();  // protect B-region overwrite
            // stage gt B-frags: points [g*1024, g*1024+1024)
            for (int i = tid; i < 1024; i += 256) {
                const float* pp = qp + (size_t)(g * 1024 + i) * 3;
                float x = pp[0], y = pp[1], z = pp[2];
                H8 bf; bf.q4 = make_uint4(0, 0, 0, 0);
                bf.h[0] = (_Float16)(-2.f * x); bf.h[1] = (_Float16)(-2.f * y);
                bf.h[2] = (_Float16)(-2.f * z); bf.h[3] = (_Float16)1.f;
                bf.h[4] = (_Float16)(x * x + y * y + z * z);
                s_frag4[(i >> 5) * 33 + (i & 31)] = bf.q4;
            }
            __syncthreads();
            if (g == 0) a.q4 = *(const uint4*)(aBase + w * 528);  // wave's sp A-tile
#pragma unroll
            for (int t = 0; t < 32; t += 2) {
                H8 b0; b0.q4 = *(const uint4*)(bBase + t * 528);
                H8 b1; b1.q4 = *(const uint4*)(bBase + (t + 1) * 528);
                float16 d0 = __builtin_amdgcn_mfma_f32_32x32x16_f16(a.v, b0.v, z16, 0, 0, 0);
                float16 d1 = __builtin_amdgcn_mfma_f32_32x32x16_f16(a.v, b1.v, z16, 0, 0, 0);
#pragma unroll
                for (int r = 0; r < 16; r++) rm[r] = min3f(rm[r], d0[r], d1[r]);
            }
        }
        // wave-local: min over lanes (gt cols) -> sum this wave's 32 sp rows
        float tsum = 0.f;
#pragma unroll
        for (int r = 0; r < 16; r++) tsum += wave32_min(rm[r]);
        tsum += __shfl_xor(tsum, 32, 64);  // add other half's 16 rows
        if (lane == 0) redbuf[w] = tsum;
        __syncthreads();
        if (tid == 0) {
            float scale = (bb < 8) ? 1.f / (2.f * 3.f * 8.f * 1024.f)
                                   : 1.f / (2.f * 3.f * 16.f * 1024.f);
            partials[bid] = (redbuf[0] + redbuf[1] + redbuf[2] + redbuf[3]) * scale;
        }
    } else {
        // ---------------- row pass: gt-side min (over sp), block-local ----------------
        int rbid = bid - 192;
        int bb = rbid >> 5;        // 24 batches
        int mc = rbid & 31;        // 512-row gt chunk
        const float* spp = (bb < 8) ? sp + (size_t)bb * SPTS * 3
                                    : tsp + (size_t)(bb - 8) * SPTS * 3;
        const float* qp  = (bb < 8) ? gt + (size_t)bb * NPTS * 3
                                    : tgt + (size_t)(bb - 8) * NPTS * 3;

        // zero slots for all 48 tiles (32 sp B + 16 gt A)
        if (tid < 48) s_frag4[tid * 33 + 32] = make_uint4(0, 0, 0, 0);
        // stage sp B-frags (1024 points)
        for (int i = tid; i < 1024; i += 256) {
            const float* pp = spp + (size_t)i * 3;
            float sx = pp[0], sy = pp[1], sz = pp[2];
            H8 bf; bf.q4 = make_uint4(0, 0, 0, 0);
            bf.h[0] = (_Float16)(-2.f * sx); bf.h[1] = (_Float16)(-2.f * sy);
            bf.h[2] = (_Float16)(-2.f * sz); bf.h[3] = (_Float16)1.f;
            bf.h[4] = (_Float16)(sx * sx + sy * sy + sz * sz);
            s_frag4[(i >> 5) * 33 + (i & 31)] = bf.q4;
        }
        // stage gt A-frags (512 points of this chunk)
        for (int i = tid; i < 512; i += 256) {
            const float* pp = qp + (size_t)(mc * 512 + i) * 3;
            float x = pp[0], y = pp[1], z = pp[2];
            H8 af; af.q4 = make_uint4(0, 0, 0, 0);
            af.h[0] = (_Float16)x; af.h[1] = (_Float16)y; af.h[2] = (_Float16)z;
            af.h[3] = (_Float16)(x * x + y * y + z * z); af.h[4] = (_Float16)1.f;
            s_frag4[1056 + (i >> 5) * 33 + (i & 31)] = af.q4;
        }
        __syncthreads();

        const char* lds = (const char*)s_frag4;
        const int laneoff = (lane < 32) ? lh * 16 : 512;
        const char* bBase = lds + laneoff;
        const char* aBase = lds + 1056 * 16 + laneoff;

        float wsum = 0.f;
        for (int mi = 0; mi < 4; mi++) {
            int mt = w * 4 + mi;  // this wave's m-tile (0..15)
            H8 a; a.q4 = *(const uint4*)(aBase + mt * 528);
            float rm[16];
#pragma unroll
            for (int r = 0; r < 16; r++) rm[r] = 1e30f;
#pragma unroll
            for (int t = 0; t < 32; t += 2) {
                H8 b0; b0.q4 = *(const uint4*)(bBase + t * 528);
                H8 b1; b1.q4 = *(const uint4*)(bBase + (t + 1) * 528);
                float16 d0 = __builtin_amdgcn_mfma_f32_32x32x16_f16(a.v, b0.v, z16, 0, 0, 0);
                float16 d1 = __builtin_amdgcn_mfma_f32_32x32x16_f16(a.v, b1.v, z16, 0, 0, 0);
#pragma unroll
                for (int r = 0; r < 16; r++) rm[r] = min3f(rm[r], d0[r], d1[r]);
            }
            float tsum = 0.f;
#pragma unroll
            for (int r = 0; r < 16; r++) tsum += wave32_min(rm[r]);
            wsum += tsum;
        }
        wsum += __shfl_xor(wsum, 32, 64);
        if (lane == 0) redbuf[w] = wsum;
        __syncthreads();
        if (tid == 0) {
            float scale = (bb < 8) ? 1.f / (2.f * 3.f * 8.f * 16384.f)
                                   : 1.f / (2.f * 3.f * 16.f * 16384.f);
            partials[bid] = (redbuf[0] + redbuf[1] + redbuf[2] + redbuf[3]) * scale;
        }
    }

    // ---------------- master counter: last block sums all partials -> out ----------------
    __syncthreads();
    if (tid == 0) {
        __threadfence();
        unsigned int old = atomicAdd(&counters[0], 1u);
        flag = (old == 1023u);
    }
    __syncthreads();
    if (flag) {
        __threadfence();
        float s2 = 0.f;
        for (int i = tid; i < 1024; i += 256) s2 += partials[i];
        for (int o = 32; o > 0; o >>= 1) s2 += __shfl_down(s2, o, 64);
        if (lane == 0) redbuf[w] = s2;
        __syncthreads();
        if (tid == 0) out[0] = redbuf[0] + redbuf[1] + redbuf[2] + redbuf[3];
    }
}

extern "C" void kernel_launch(void* const* d_in, const int* in_sizes, int n_in,
                              void* d_out, int out_size, void* d_ws, size_t ws_size,
                              hipStream_t stream) {
    const float* gt  = (const float*)d_in[0];  // gt_points [8,16384,3]
    const float* sp  = (const float*)d_in[1];  // structure_points [8,1024,3]
    const float* tgt = (const float*)d_in[2];  // transed_gt_points [2,8,16384,3]
    const float* tsp = (const float*)d_in[3];  // transed_structure_points [2,8,1024,3]
    const float* tm  = (const float*)d_in[4];  // trans_mats [2,3,3]

    unsigned int* counters = (unsigned int*)d_ws;
    float* partials = (float*)((char*)d_ws + 64);  // 1024 floats

    hipMemsetAsync(d_ws, 0, 64, stream);  // master counter

    fused_kernel<<<1024, 256, 0, stream>>>(gt, sp, tgt, tsp, tm, counters, partials,
                                           (float*)d_out);
}

// Round 8
// 114.951 us; speedup vs baseline: 1.3292x; 1.1335x over previous
//
#include <hip/hip_runtime.h>

// Problem constants: B=8, N=16384, S=1024, T=2, D=3
#define NPTS 16384
#define SPTS 1024

typedef _Float16 half8 __attribute__((ext_vector_type(8)));
typedef float float16 __attribute__((ext_vector_type(16)));

union H8 { _Float16 h[8]; half8 v; uint4 q4; };

// min across each 32-lane half (validated r6/r7, absmax 0)
__device__ inline float wave32_min(float v) {
    v = fminf(v, __int_as_float(__builtin_amdgcn_mov_dpp(__float_as_int(v), 0xB1, 0xF, 0xF, true)));
    v = fminf(v, __int_as_float(__builtin_amdgcn_mov_dpp(__float_as_int(v), 0x4E, 0xF, 0xF, true)));
    v = fminf(v, __int_as_float(__builtin_amdgcn_mov_dpp(__float_as_int(v), 0x141, 0xF, 0xF, true)));
    v = fminf(v, __int_as_float(__builtin_amdgcn_mov_dpp(__float_as_int(v), 0x140, 0xF, 0xF, true)));
    v = fminf(v, __int_as_float(__builtin_amdgcn_ds_swizzle(__float_as_int(v), 0x401F)));
    return v;
}

// 3-way min shaped for LLVM's v_min3_f32 fusion (no inline asm: r9 hazard lesson).
__device__ inline float min3f(float a, float b, float c) {
    return fminf(fminf(a, b), c);
}

// r16. r15 counters: Occ 19.7%, MfmaUtil 13, VALUBusy 24, warm 71us vs ~17us of
// arithmetic -> grid-shape latency: 192 col blocks (512 MFMA/wave, 16 serial
// sync rounds) are a 4x-long pole vs 768 row blocks (128 MFMA/wave).
// Fix: HOMOGENEOUS grid of 768 = exactly 3 blocks/CU at (256,3):
//   [0,384):   col blocks, 64 sp x all 16384 gt, DOUBLE-BUFFERED staging
//              (stage g+1 while computing g, 1 barrier/round). 256 MFMA/wave.
//   [384,768): row blocks, 1024 gt rows x all 1024 sp. 256 MFMA/wave.
//              rbid<64 also do the consistency-MSE prelude (tiny).
// Every wave: 256 MFMAs. One resident generation, no tail.
// RULES kept: (256,3) cap 170 VGPR (r8/r14 spill cliff at (256,4)); no inline
// asm on MFMA results (r9); 2-deep MFMA; plain stores + completion counter.

__global__ __launch_bounds__(256, 3) void fused_kernel(
    const float* __restrict__ gt,   // [8,16384,3]
    const float* __restrict__ sp,   // [8,1024,3]
    const float* __restrict__ tgt,  // [16,16384,3]
    const float* __restrict__ tsp,  // [16,1024,3]
    const float* __restrict__ tm,   // [2,3,3]
    unsigned int* __restrict__ counters,  // [0]=master
    float* __restrict__ partials,         // [768]
    float* __restrict__ out)
{
    const int bid = blockIdx.x;
    const int tid = threadIdx.x;
    const int lane = tid & 63;
    const int lh = lane & 31;
    const int w = tid >> 6;  // wave 0..3

    // col: B dbuf [0,1056)+[1056,2112), A 2 tiles [2112,2178)
    // row: B sp [0,1056), A gt [1056,2112)
    __shared__ uint4 s_frag4[2178];  // 34.8 KB; 3 blocks/CU -> 104.5 KB/CU ok
    __shared__ float redbuf[4];
    __shared__ float redbufM[4];
    __shared__ float cmerge[128];
    __shared__ int flag;

    float16 z16 = {0.f,0.f,0.f,0.f,0.f,0.f,0.f,0.f,0.f,0.f,0.f,0.f,0.f,0.f,0.f,0.f};

    if (bid < 384) {
        // ---- col pass: sp-side min (over gt). 384 blocks x 64 sp, dbuf staging ----
        int bb = bid >> 4;         // 24 batches
        int sc = bid & 15;         // 64-point sp chunk
        const float* spp = (bb < 8) ? sp + (size_t)bb * SPTS * 3
                                    : tsp + (size_t)(bb - 8) * SPTS * 3;
        const float* qp  = (bb < 8) ? gt + (size_t)bb * NPTS * 3
                                    : tgt + (size_t)(bb - 8) * NPTS * 3;

        // zero slots: 64 B-buffer tiles (both buffers) + 2 A tiles
        if (tid < 64) s_frag4[(tid >> 5) * 1056 + (tid & 31) * 33 + 32] = make_uint4(0, 0, 0, 0);
        if (tid < 2)  s_frag4[2112 + tid * 33 + 32] = make_uint4(0, 0, 0, 0);
        // stage A-frags: this block's 64 sp points (A format: [x,y,z,|p|^2,1])
        if (tid < 64) {
            const float* pp = spp + (size_t)(sc * 64 + tid) * 3;
            float sx = pp[0], sy = pp[1], sz = pp[2];
            H8 af; af.q4 = make_uint4(0, 0, 0, 0);
            af.h[0] = (_Float16)sx; af.h[1] = (_Float16)sy; af.h[2] = (_Float16)sz;
            af.h[3] = (_Float16)(sx * sx + sy * sy + sz * sz); af.h[4] = (_Float16)1.f;
            s_frag4[2112 + (tid >> 5) * 33 + (tid & 31)] = af.q4;
        }
        // prologue: stage g=0 into buf0
        for (int i = tid; i < 1024; i += 256) {
            const float* pp = qp + (size_t)i * 3;
            float x = pp[0], y = pp[1], z = pp[2];
            H8 bf; bf.q4 = make_uint4(0, 0, 0, 0);
            bf.h[0] = (_Float16)(-2.f * x); bf.h[1] = (_Float16)(-2.f * y);
            bf.h[2] = (_Float16)(-2.f * z); bf.h[3] = (_Float16)1.f;
            bf.h[4] = (_Float16)(x * x + y * y + z * z);
            s_frag4[(i >> 5) * 33 + (i & 31)] = bf.q4;
        }
        __syncthreads();

        const char* lds = (const char*)s_frag4;
        const int laneoff = (lane < 32) ? lh * 16 : 512;
        const int at = w & 1;      // this wave's A tile (sp 32-chunk)
        const int hf = w >> 1;     // this wave's gt half: B tiles [hf*16, hf*16+16)
        H8 a; a.q4 = *(const uint4*)(lds + 2112 * 16 + laneoff + at * 528);

        float rm[16];
#pragma unroll
        for (int r = 0; r < 16; r++) rm[r] = 1e30f;

        for (int g = 0; g < 16; g++) {
            int cur = g & 1;
            // stage g+1 into the other buffer (overlaps with compute below)
            if (g < 15) {
                const float* qg = qp + (size_t)(g + 1) * 1024 * 3;
                int bufo = (cur ^ 1) * 1056;
                for (int i = tid; i < 1024; i += 256) {
                    const float* pp = qg + (size_t)i * 3;
                    float x = pp[0], y = pp[1], z = pp[2];
                    H8 bf; bf.q4 = make_uint4(0, 0, 0, 0);
                    bf.h[0] = (_Float16)(-2.f * x); bf.h[1] = (_Float16)(-2.f * y);
                    bf.h[2] = (_Float16)(-2.f * z); bf.h[3] = (_Float16)1.f;
                    bf.h[4] = (_Float16)(x * x + y * y + z * z);
                    s_frag4[bufo + (i >> 5) * 33 + (i & 31)] = bf.q4;
                }
            }
            // compute on buf[cur]: this wave's 16 B tiles
            const char* bBase = lds + cur * 1056 * 16 + laneoff + (size_t)(hf * 16) * 528;
#pragma unroll
            for (int j = 0; j < 16; j += 2) {
                H8 b0; b0.q4 = *(const uint4*)(bBase + j * 528);
                H8 b1; b1.q4 = *(const uint4*)(bBase + (j + 1) * 528);
                float16 d0 = __builtin_amdgcn_mfma_f32_32x32x16_f16(a.v, b0.v, z16, 0, 0, 0);
                float16 d1 = __builtin_amdgcn_mfma_f32_32x32x16_f16(a.v, b1.v, z16, 0, 0, 0);
#pragma unroll
                for (int r = 0; r < 16; r++) rm[r] = min3f(rm[r], d0[r], d1[r]);
            }
            __syncthreads();  // staging of g+1 complete; buf[cur] free to overwrite
        }
        // wave-local: min over 32 lanes (gt cols) -> per-sp-row mins for this half
        if (lh == 0) {
            int hi = lane >> 5;
#pragma unroll
            for (int r = 0; r < 16; r++) {
                // note: wave32_min inside the loop (uniform lh==0 branch is fine:
                // all lanes execute wave32_min, only lh==0 stores)
            }
        }
        {
#pragma unroll
            for (int r = 0; r < 16; r++) {
                float wm = wave32_min(rm[r]);
                if (lh == 0) {
                    int hi = lane >> 5;
                    cmerge[w * 32 + (r & 3) + 8 * (r >> 2) + 4 * hi] = wm;
                }
            }
        }
        __syncthreads();
        if (tid < 64) {
            int a_t = tid >> 5, m = tid & 31;
            float v = fminf(cmerge[a_t * 32 + m], cmerge[(a_t + 2) * 32 + m]);
            float scale = (bb < 8) ? 1.f / (2.f * 3.f * 8.f * 1024.f)
                                   : 1.f / (2.f * 3.f * 16.f * 1024.f);
            float s = v * scale;
            for (int o = 32; o > 0; o >>= 1) s += __shfl_down(s, o, 64);
            if (tid == 0) partials[bid] = s;
        }
    } else {
        // ---- row pass: gt-side min (over sp). 384 blocks x 1024 gt rows ----
        int rbid = bid - 384;
        int bb = rbid >> 4;        // 24 batches
        int mc = rbid & 15;        // 1024-row gt chunk
        const float* spp = (bb < 8) ? sp + (size_t)bb * SPTS * 3
                                    : tsp + (size_t)(bb - 8) * SPTS * 3;
        const float* qp  = (bb < 8) ? gt + (size_t)bb * NPTS * 3
                                    : tgt + (size_t)(bb - 8) * NPTS * 3;

        // consistency-MSE prelude on row blocks 0..63 (1 point/thread)
        float mse = 0.f;
        if (lane == 0) redbufM[w] = 0.f;
        if (rbid < 64) {
            int idx = rbid * 256 + tid;  // over (t,b,s) = 2*8*1024
            int t = idx >> 13;
            int bs = idx & 8191;
            const float* p = sp + (size_t)bs * 3;
            float x = p[0], y = p[1], z = p[2];
            const float* m = tm + t * 9;
            const float* q = tsp + (size_t)idx * 3;
#pragma unroll
            for (int e = 0; e < 3; e++) {
                float v = fmaf(x, m[e], fmaf(y, m[3 + e], z * m[6 + e]));
                float d = v - q[e];
                mse = fmaf(d, d, mse);
            }
            for (int o = 32; o > 0; o >>= 1) mse += __shfl_down(mse, o, 64);
            if (lane == 0) redbufM[w] = mse;
        }

        // zero slots: 32 sp B tiles + 32 gt A tiles
        if (tid < 64) s_frag4[(tid >> 5) * 1056 + (tid & 31) * 33 + 32] = make_uint4(0, 0, 0, 0);
        // stage sp B-frags (1024 points)
        for (int i = tid; i < 1024; i += 256) {
            const float* pp = spp + (size_t)i * 3;
            float sx = pp[0], sy = pp[1], sz = pp[2];
            H8 bf; bf.q4 = make_uint4(0, 0, 0, 0);
            bf.h[0] = (_Float16)(-2.f * sx); bf.h[1] = (_Float16)(-2.f * sy);
            bf.h[2] = (_Float16)(-2.f * sz); bf.h[3] = (_Float16)1.f;
            bf.h[4] = (_Float16)(sx * sx + sy * sy + sz * sz);
            s_frag4[(i >> 5) * 33 + (i & 31)] = bf.q4;
        }
        // stage gt A-frags (1024 rows of this chunk)
        for (int i = tid; i < 1024; i += 256) {
            const float* pp = qp + (size_t)(mc * 1024 + i) * 3;
            float x = pp[0], y = pp[1], z = pp[2];
            H8 af; af.q4 = make_uint4(0, 0, 0, 0);
            af.h[0] = (_Float16)x; af.h[1] = (_Float16)y; af.h[2] = (_Float16)z;
            af.h[3] = (_Float16)(x * x + y * y + z * z); af.h[4] = (_Float16)1.f;
            s_frag4[1056 + (i >> 5) * 33 + (i & 31)] = af.q4;
        }
        __syncthreads();

        const char* lds = (const char*)s_frag4;
        const int laneoff = (lane < 32) ? lh * 16 : 512;
        const char* bBase = lds + laneoff;
        const char* aBase = lds + 1056 * 16 + laneoff;

        float wsum = 0.f;
        for (int mi = 0; mi < 8; mi++) {
            int mt = w * 8 + mi;  // this wave's m-tile (0..31)
            H8 a; a.q4 = *(const uint4*)(aBase + mt * 528);
            float rm[16];
#pragma unroll
            for (int r = 0; r < 16; r++) rm[r] = 1e30f;
#pragma unroll
            for (int t = 0; t < 32; t += 2) {
                H8 b0; b0.q4 = *(const uint4*)(bBase + t * 528);
                H8 b1; b1.q4 = *(const uint4*)(bBase + (t + 1) * 528);
                float16 d0 = __builtin_amdgcn_mfma_f32_32x32x16_f16(a.v, b0.v, z16, 0, 0, 0);
                float16 d1 = __builtin_amdgcn_mfma_f32_32x32x16_f16(a.v, b1.v, z16, 0, 0, 0);
#pragma unroll
                for (int r = 0; r < 16; r++) rm[r] = min3f(rm[r], d0[r], d1[r]);
            }
            float tsum = 0.f;
#pragma unroll
            for (int r = 0; r < 16; r++) tsum += wave32_min(rm[r]);
            wsum += tsum;
        }
        wsum += __shfl_xor(wsum, 32, 64);
        if (lane == 0) redbuf[w] = wsum;
        __syncthreads();
        if (tid == 0) {
            float scale = (bb < 8) ? 1.f / (2.f * 3.f * 8.f * 16384.f)
                                   : 1.f / (2.f * 3.f * 16.f * 16384.f);
            partials[bid] = (redbuf[0] + redbuf[1] + redbuf[2] + redbuf[3]) * scale
                          + (redbufM[0] + redbufM[1] + redbufM[2] + redbufM[3])
                            * (1000.f / (2.f * 8.f * 1024.f * 3.f));
        }
    }

    // ---------------- master counter: last block sums all partials -> out ----------------
    __syncthreads();
    if (tid == 0) {
        __threadfence();
        unsigned int old = atomicAdd(&counters[0], 1u);
        flag = (old == 767u);
    }
    __syncthreads();
    if (flag) {
        __threadfence();
        float s2 = 0.f;
        for (int i = tid; i < 768; i += 256) s2 += partials[i];
        for (int o = 32; o > 0; o >>= 1) s2 += __shfl_down(s2, o, 64);
        if (lane == 0) redbuf[w] = s2;
        __syncthreads();
        if (tid == 0) out[0] = redbuf[0] + redbuf[1] + redbuf[2] + redbuf[3];
    }
}

extern "C" void kernel_launch(void* const* d_in, const int* in_sizes, int n_in,
                              void* d_out, int out_size, void* d_ws, size_t ws_size,
                              hipStream_t stream) {
    const float* gt  = (const float*)d_in[0];  // gt_points [8,16384,3]
    const float* sp  = (const float*)d_in[1];  // structure_points [8,1024,3]
    const float* tgt = (const float*)d_in[2];  // transed_gt_points [2,8,16384,3]
    const float* tsp = (const float*)d_in[3];  // transed_structure_points [2,8,1024,3]
    const float* tm  = (const float*)d_in[4];  // trans_mats [2,3,3]

    unsigned int* counters = (unsigned int*)d_ws;
    float* partials = (float*)((char*)d_ws + 64);  // 768 floats

    hipMemsetAsync(d_ws, 0, 64, stream);  // master counter

    fused_kernel<<<768, 256, 0, stream>>>(gt, sp, tgt, tsp, tm, counters, partials,
                                          (float*)d_out);
}